// Round 1
// baseline (136.007 us; speedup 1.0000x reference)
//
#include <hip/hip_runtime.h>
#include <math.h>

#define BLK   256
#define ROWS  256
#define DD    128
#define NN    15      // internal nodes
#define NL    16      // leaves
#define OC    16      // 2*A outputs per leaf
#define AO    8       // A
#define OSTR  20      // padded LDS stride for out rows (floats)

__global__ __launch_bounds__(BLK, 4)
void dts_fused(const float* __restrict__ x, const float* __restrict__ Wn,
               const float* __restrict__ bn, const float* __restrict__ Wl,
               const float* __restrict__ bl, float* __restrict__ out, int B)
{
    __shared__ __align__(16) float sWnT[NN][DD];     // Wn transposed: [node][d]
    __shared__ float sBn[NN];
    __shared__ __align__(16) float sBl[NL * OC];
    __shared__ __align__(16) float sOut[ROWS][OSTR]; // un-permute buffer
    __shared__ int sPerm[ROWS];
    __shared__ int sLeafS[ROWS];
    __shared__ int sBins[NL];
    __shared__ int sStarts[NL];

    const int t = threadIdx.x;
    const int rowBase = blockIdx.x * ROWS;
    if (rowBase >= B) return;

    // ---- stage weights ----
    for (int i = t; i < NN * DD; i += BLK) {
        int d = i / NN, n = i - d * NN;   // Wn layout [D][NN]
        sWnT[n][d] = Wn[i];
    }
    if (t < NN) sBn[t] = bn[t];
    for (int i = t; i < NL * OC; i += BLK) sBl[i] = bl[i];
    if (t < NL) sBins[t] = 0;
    __syncthreads();

    // ---- phase 1: node logits + argmax leaf (thread t -> row rowBase+t) ----
    float acc[NN];
    #pragma unroll
    for (int n = 0; n < NN; ++n) acc[n] = 0.0f;

    const float4* xr = reinterpret_cast<const float4*>(x + (size_t)(rowBase + t) * DD);
    #pragma unroll 4
    for (int d4 = 0; d4 < DD / 4; ++d4) {
        float4 xv = xr[d4];
        #pragma unroll
        for (int n = 0; n < NN; ++n) {
            float4 w = *reinterpret_cast<const float4*>(&sWnT[n][d4 * 4]);
            acc[n] = fmaf(xv.w, w.w, fmaf(xv.z, w.z, fmaf(xv.y, w.y, fmaf(xv.x, w.x, acc[n]))));
        }
    }
    #pragma unroll
    for (int n = 0; n < NN; ++n) acc[n] += sBn[n];

    // tree-expand leaf logits: leaf bits MSB-first, left(bit0)=+, right(bit1)=-
    float L2a[4], L3a[8], L4a[16];
    {
        float p = acc[0], m = -acc[0];
        L2a[0] = p + acc[1]; L2a[1] = p - acc[1];
        L2a[2] = m + acc[2]; L2a[3] = m - acc[2];
        #pragma unroll
        for (int i = 0; i < 4; ++i) { L3a[2*i] = L2a[i] + acc[3+i]; L3a[2*i+1] = L2a[i] - acc[3+i]; }
        #pragma unroll
        for (int i = 0; i < 8; ++i) { L4a[2*i] = L3a[i] + acc[7+i]; L4a[2*i+1] = L3a[i] - acc[7+i]; }
    }
    int best = 0; float bv = L4a[0];
    #pragma unroll
    for (int l = 1; l < NL; ++l) if (L4a[l] > bv) { bv = L4a[l]; best = l; }

    // ---- counting sort rows by leaf (so waves share leaves in phase 3) ----
    int rank = atomicAdd(&sBins[best], 1);
    __syncthreads();
    if (t == 0) {
        int s = 0;
        #pragma unroll
        for (int l = 0; l < NL; ++l) { sStarts[l] = s; s += sBins[l]; }
    }
    __syncthreads();
    {
        int slot = sStarts[best] + rank;
        sPerm[slot] = t;
        sLeafS[slot] = best;
    }
    __syncthreads();

    // ---- phase 3: leaf projection, sorted order ----
    {
        const int r    = sPerm[t];      // row (within block) this thread computes
        const int leaf = sLeafS[t];
        const float4* xr2 = reinterpret_cast<const float4*>(x + (size_t)(rowBase + r) * DD);
        const float4* wl  = reinterpret_cast<const float4*>(Wl + (size_t)leaf * DD * OC);

        const float4* blv = reinterpret_cast<const float4*>(&sBl[leaf * OC]);
        float4 o0 = blv[0], o1 = blv[1], o2 = blv[2], o3 = blv[3];

        #define STEP(xs, dd) { \
            float4 w0 = wl[(dd)*4+0]; float4 w1 = wl[(dd)*4+1]; \
            float4 w2 = wl[(dd)*4+2]; float4 w3 = wl[(dd)*4+3]; \
            o0.x = fmaf((xs), w0.x, o0.x); o0.y = fmaf((xs), w0.y, o0.y); \
            o0.z = fmaf((xs), w0.z, o0.z); o0.w = fmaf((xs), w0.w, o0.w); \
            o1.x = fmaf((xs), w1.x, o1.x); o1.y = fmaf((xs), w1.y, o1.y); \
            o1.z = fmaf((xs), w1.z, o1.z); o1.w = fmaf((xs), w1.w, o1.w); \
            o2.x = fmaf((xs), w2.x, o2.x); o2.y = fmaf((xs), w2.y, o2.y); \
            o2.z = fmaf((xs), w2.z, o2.z); o2.w = fmaf((xs), w2.w, o2.w); \
            o3.x = fmaf((xs), w3.x, o3.x); o3.y = fmaf((xs), w3.y, o3.y); \
            o3.z = fmaf((xs), w3.z, o3.z); o3.w = fmaf((xs), w3.w, o3.w); }

        #pragma unroll 2
        for (int d4 = 0; d4 < DD / 4; ++d4) {
            float4 xv = xr2[d4];
            STEP(xv.x, d4 * 4 + 0);
            STEP(xv.y, d4 * 4 + 1);
            STEP(xv.z, d4 * 4 + 2);
            STEP(xv.w, d4 * 4 + 3);
        }
        #undef STEP

        float* so = &sOut[r][0];
        *reinterpret_cast<float4*>(&so[0])  = o0;
        *reinterpret_cast<float4*>(&so[4])  = o1;
        *reinterpret_cast<float4*>(&so[8])  = o2;
        *reinterpret_cast<float4*>(&so[12]) = o3;
    }
    __syncthreads();

    // ---- coalesced write-out (thread t -> row rowBase+t) ----
    {
        const float* so = &sOut[t][0];
        float4 m0 = *reinterpret_cast<const float4*>(&so[0]);
        float4 m1 = *reinterpret_cast<const float4*>(&so[4]);
        float4 s0 = *reinterpret_cast<const float4*>(&so[8]);
        float4 s1 = *reinterpret_cast<const float4*>(&so[12]);

        size_t ob = (size_t)(rowBase + t) * AO;
        *reinterpret_cast<float4*>(&out[ob])     = m0;
        *reinterpret_cast<float4*>(&out[ob + 4]) = m1;

        // log_std = -5 + 3.5*(tanh(v)+1)
        float4 r0, r1;
        r0.x = -5.0f + 3.5f * (tanhf(s0.x) + 1.0f);
        r0.y = -5.0f + 3.5f * (tanhf(s0.y) + 1.0f);
        r0.z = -5.0f + 3.5f * (tanhf(s0.z) + 1.0f);
        r0.w = -5.0f + 3.5f * (tanhf(s0.w) + 1.0f);
        r1.x = -5.0f + 3.5f * (tanhf(s1.x) + 1.0f);
        r1.y = -5.0f + 3.5f * (tanhf(s1.y) + 1.0f);
        r1.z = -5.0f + 3.5f * (tanhf(s1.z) + 1.0f);
        r1.w = -5.0f + 3.5f * (tanhf(s1.w) + 1.0f);

        size_t ob2 = (size_t)B * AO + ob;
        *reinterpret_cast<float4*>(&out[ob2])     = r0;
        *reinterpret_cast<float4*>(&out[ob2 + 4]) = r1;
    }
}

extern "C" void kernel_launch(void* const* d_in, const int* in_sizes, int n_in,
                              void* d_out, int out_size, void* d_ws, size_t ws_size,
                              hipStream_t stream)
{
    const float* x  = (const float*)d_in[0];
    const float* Wn = (const float*)d_in[1];
    const float* bn = (const float*)d_in[2];
    const float* Wl = (const float*)d_in[3];
    const float* bl = (const float*)d_in[4];
    float* out = (float*)d_out;

    const int B = in_sizes[0] / DD;          // 262144
    const int blocks = (B + ROWS - 1) / ROWS; // 1024

    hipLaunchKernelGGL(dts_fused, dim3(blocks), dim3(BLK), 0, stream,
                       x, Wn, bn, Wl, bl, out, B);
}